// Round 3
// baseline (565.965 us; speedup 1.0000x reference)
//
#include <hip/hip_runtime.h>

#define H 448
#define W 448
#define CIN 64
#define COUT 64
#define NBATCH 4
#define BS 14
#define HW (H * W)
#define PITCH 72   // bf16 per pixel row in A-tile (16B aligned; 36 dw = 4 mod 32 banks)
#define EPIP 68    // f32 pitch in wave-private epilogue buf (4 mod 32)

// ws layout (bytes)
#define WS_CNT 0       // uint counter (memset to 0 each launch)
#define WS_LIST 64     // uint[512] strip list
#define WS_ACT 4096    // uchar[4096] per-block activity
#define WS_WB 8192     // bf16 weight fragments, 73728 B

typedef __attribute__((ext_vector_type(8))) short short8;
typedef __attribute__((ext_vector_type(4))) float f32x4;

static __device__ __forceinline__ unsigned short f2bf(float f) {
  unsigned u = __float_as_uint(f);
  u += 0x7FFF + ((u >> 16) & 1);  // RNE
  return (unsigned short)(u >> 16);
}

// Weights -> B-fragment order: wB[((kk*4+nt)*64+lane)*8+j] = bf16(W[k][n]),
// k = kk*32 + (lane>>4)*8 + j = tap*64 + c, n = nt*16 + (lane&15).
__global__ __launch_bounds__(256) void prep_wB(const float* __restrict__ w,
                                               unsigned short* __restrict__ wB) {
  int e = blockIdx.x * 256 + threadIdx.x;
  if (e >= 18 * 4 * 64 * 8) return;
  int j = e & 7, lane = (e >> 3) & 63, nt = (e >> 9) & 3, kk = e >> 11;
  int k = kk * 32 + (lane >> 4) * 8 + j;
  int tap = k >> 6, c = k & 63;
  int n = nt * 16 + (lane & 15);
  wB[e] = f2bf(w[(n * CIN + c) * 9 + tap]);
}

// K1: per-block activity; zero-fill fully-inactive strips (aligned 448B rows);
// append active strips to list.
__global__ __launch_bounds__(256) void plan_zero(
    const float* __restrict__ mask, float* __restrict__ out,
    unsigned* __restrict__ cnt, unsigned* __restrict__ list,
    unsigned char* __restrict__ act) {
  const int sx = blockIdx.x, by = blockIdx.y, n = blockIdx.z;
  const int t = threadIdx.x;
  const int wy = t >> 4, wx = t & 15;
  const int gy = by * BS - 1 + wy;
  const bool rowok = (gy >= 0 && gy < H);
  int strip_any = 0;
  for (int jb = 0; jb < 8; ++jb) {
    int bx = sx * 8 + jb;
    int gx = bx * BS - 1 + wx;
    int p = rowok && gx >= 0 && gx < W && mask[(n * H + gy) * W + gx] > 0.5f;
    int a = __syncthreads_or(p);
    if (t == 0) act[(n * 32 + by) * 32 + bx] = (unsigned char)a;
    strip_any |= a;
  }
  if (!strip_any) {
    const float4 z = {0.f, 0.f, 0.f, 0.f};
    const int x0 = sx * 112;
    for (int idx = t; idx < COUT * BS * 28; idx += 256) {
      int c = idx / (BS * 28);
      int r = idx - c * (BS * 28);
      int y = r / 28, q = r - y * 28;
      *(float4*)(out + ((size_t)(n * COUT + c) * H + by * BS + y) * W + x0 +
                 q * 4) = z;
    }
  } else if (t == 0) {
    unsigned i = atomicAdd(cnt, 1u);
    list[i] = (unsigned)((n * 32 + by) * 4 + sx);
  }
}

// K2: one strip of 8 blocks per WG, register-prefetch pipeline across blocks.
__global__ __launch_bounds__(256, 2) void conv_strips(
    const float* __restrict__ x, const unsigned short* __restrict__ wB,
    const float* __restrict__ bias, float* __restrict__ out,
    const unsigned* __restrict__ cnt, const unsigned* __restrict__ list,
    const unsigned char* __restrict__ act) {
  __shared__ short tileS[256 * PITCH];       // 36864 B A-tile
  __shared__ float epiS[4 * 16 * EPIP];      // 17408 B wave-private epilogue
  __shared__ float biasS[COUT];

  const unsigned nstrip = *cnt;
  if (blockIdx.x >= nstrip) return;
  const unsigned sid = list[blockIdx.x];
  const int sx = sid & 3, by = (sid >> 2) & 31, n = sid >> 7;
  const int t = threadIdx.x;
  const int wv = t >> 6, lane = t & 63, quad = lane >> 4, lrow = lane & 15;
  const int qoff = quad * 8;

  if (t < COUT) biasS[t] = bias[t];

  char a8[9];
#pragma unroll
  for (int j = 0; j < 8; ++j) a8[j] = act[(n * 32 + by) * 32 + sx * 8 + j];
  a8[8] = 0;

  // staging coords (thread = pixel)
  const int iy = t >> 4, ix = t & 15;
  const int gy = by * BS - 1 + iy;
  const bool rowok = (gy >= 0 && gy < H);

  // MFMA A-fragment bases
  const int nmt = (wv == 0) ? 4 : 3;
  int abase[4];
#pragma unroll
  for (int i = 0; i < 4; ++i) {
    int mt = wv + 4 * i;
    int m = mt * 16 + lrow;
    if (m > 195) m = 195;
    int oy = m / 14, ox = m - oy * 14;
    abase[i] = (oy * 16 + ox) * PITCH;
  }

  __syncthreads();  // biasS visible
  float bias4[4];
#pragma unroll
  for (int nt = 0; nt < 4; ++nt) bias4[nt] = biasS[nt * 16 + lrow];

  const short8* wB8 = (const short8*)wB;
  float* ep = epiS + wv * 16 * EPIP;

  float R[64];
  // prologue: raw-load block 0 (selection deferred to pack)
  if (a8[0]) {
    int gx = (sx * 8) * BS - 1 + ix;
    bool inb = rowok && gx >= 0 && gx < W;
    const float* xp = x + (size_t)n * CIN * HW + (inb ? (gy * W + gx) : 0);
#pragma unroll
    for (int c = 0; c < 64; ++c) R[c] = xp[(size_t)c * HW];
  }

#pragma unroll 1
  for (int j = 0; j < 8; ++j) {
    const int bx = sx * 8 + j;
    if (a8[j]) {
      // recompute in-bounds for THIS block (R holds raw loads)
      int gxj = bx * BS - 1 + ix;
      bool inbj = rowok && gxj >= 0 && gxj < W;
      __syncthreads();  // prev kk-loop reads done; drains R (its use point)
#pragma unroll
      for (int c8 = 0; c8 < 8; ++c8) {
        float v[8];
#pragma unroll
        for (int q = 0; q < 8; ++q) v[q] = inbj ? R[c8 * 8 + q] : 0.f;
        int4 pk;
        pk.x = (int)f2bf(v[0]) | ((int)f2bf(v[1]) << 16);
        pk.y = (int)f2bf(v[2]) | ((int)f2bf(v[3]) << 16);
        pk.z = (int)f2bf(v[4]) | ((int)f2bf(v[5]) << 16);
        pk.w = (int)f2bf(v[6]) | ((int)f2bf(v[7]) << 16);
        *(int4*)(tileS + t * PITCH + c8 * 8) = pk;
      }
      __syncthreads();

      f32x4 acc[4][4];
#pragma unroll
      for (int i = 0; i < 4; ++i)
#pragma unroll
        for (int nt = 0; nt < 4; ++nt) acc[i][nt] = (f32x4){0.f, 0.f, 0.f, 0.f};

      short8 bnxt[4];
#pragma unroll
      for (int nt = 0; nt < 4; ++nt) bnxt[nt] = wB8[nt * 64 + lane];

#pragma unroll 2
      for (int kk = 0; kk < 18; ++kk) {
        short8 bcur[4];
#pragma unroll
        for (int nt = 0; nt < 4; ++nt) bcur[nt] = bnxt[nt];
        if (kk < 17) {
#pragma unroll
          for (int nt = 0; nt < 4; ++nt)
            bnxt[nt] = wB8[((kk + 1) * 4 + nt) * 64 + lane];
        }
        int tap = kk >> 1;
        int ky = tap / 3, kx = tap - 3 * ky;
        int ko = (ky * 16 + kx) * PITCH + (kk & 1) * 32 + qoff;
#pragma unroll
        for (int i = 0; i < 4; ++i) {
          if (i < nmt) {
            short8 av = *(const short8*)(tileS + abase[i] + ko);
#pragma unroll
            for (int nt = 0; nt < 4; ++nt)
              acc[i][nt] = __builtin_amdgcn_mfma_f32_16x16x32_bf16(
                  av, bcur[nt], acc[i][nt], 0, 0, 0);
          }
        }
      }

      // prefetch next block AFTER all B-loads (vmcnt FIFO) — hidden by epilogue
      if (a8[j + 1]) {
        int gx = (bx + 1) * BS - 1 + ix;
        bool inb = rowok && gx >= 0 && gx < W;
        const float* xp = x + (size_t)n * CIN * HW + (inb ? (gy * W + gx) : 0);
#pragma unroll
        for (int c = 0; c < 64; ++c) R[c] = xp[(size_t)c * HW];
      }

      // barrier-free epilogue: wave-private LDS transpose
#pragma unroll
      for (int i = 0; i < 4; ++i) {
        if (i < nmt) {
          int mt = wv + 4 * i;
#pragma unroll
          for (int nt = 0; nt < 4; ++nt)
#pragma unroll
            for (int r = 0; r < 4; ++r)
              ep[(quad * 4 + r) * EPIP + nt * 16 + lrow] =
                  acc[i][nt][r] + bias4[nt];
          __asm__ volatile("s_waitcnt lgkmcnt(0)" ::: "memory");
          int m0 = mt * 16;
#pragma unroll
          for (int it = 0; it < 16; ++it) {
            int co = it * 4 + (lane >> 4);
            int px = lane & 15;
            int m = m0 + px;
            if (m < 196) {
              int oy = m / 14, ox = m - oy * 14;
              out[((size_t)(n * COUT + co) * H + by * BS + oy) * W + bx * BS +
                  ox] = ep[px * EPIP + co];
            }
          }
          __asm__ volatile("" ::: "memory");  // keep tile reads before next write
        }
      }
    } else {
      if (a8[j + 1]) {
        int gx = (bx + 1) * BS - 1 + ix;
        bool inb = rowok && gx >= 0 && gx < W;
        const float* xp = x + (size_t)n * CIN * HW + (inb ? (gy * W + gx) : 0);
#pragma unroll
        for (int c = 0; c < 64; ++c) R[c] = xp[(size_t)c * HW];
      }
      // zero-fill inactive block inside active strip
      for (int idx = t; idx < COUT * BS * BS; idx += 256) {
        int cc = idx / (BS * BS);
        int pp = idx - cc * (BS * BS);
        int yy = pp / BS, xx = pp - yy * BS;
        out[((size_t)(n * COUT + cc) * H + by * BS + yy) * W + bx * BS + xx] =
            0.f;
      }
    }
  }
}

extern "C" void kernel_launch(void* const* d_in, const int* in_sizes, int n_in,
                              void* d_out, int out_size, void* d_ws,
                              size_t ws_size, hipStream_t stream) {
  const float* x = (const float*)d_in[0];
  const float* mask = (const float*)d_in[1];
  const float* w = (const float*)d_in[2];
  const float* bias = (const float*)d_in[3];
  float* out = (float*)d_out;
  char* ws = (char*)d_ws;

  unsigned* cnt = (unsigned*)(ws + WS_CNT);
  unsigned* list = (unsigned*)(ws + WS_LIST);
  unsigned char* act = (unsigned char*)(ws + WS_ACT);
  unsigned short* wB = (unsigned short*)(ws + WS_WB);

  hipMemsetAsync(ws, 0, 64, stream);
  prep_wB<<<dim3((18 * 4 * 64 * 8 + 255) / 256), 256, 0, stream>>>(w, wB);
  plan_zero<<<dim3(4, 32, NBATCH), 256, 0, stream>>>(mask, out, cnt, list, act);
  conv_strips<<<dim3(512), 256, 0, stream>>>(x, wB, bias, out, cnt, list, act);
}